// Round 1
// baseline (426.525 us; speedup 1.0000x reference)
//
#include <hip/hip_runtime.h>

// InverseAvgPool1d, K=8 -> half=4, stride s=9.
// out[t] = 8 * ( inclusive stride-9 prefix sum of d[t]=x[t]-x[t-1] (d[0]=0)
//                + (t % 9 == 5 ? x[0] : 0) )
// per (b,c) row of length T=4096.

#define TLEN 4096
#define NCH 9          // chains (residues mod 9)
#define SEGS 28        // segments per chain; 9*28 = 252 active threads
#define SEGLEN 17      // m-values per segment; 28*17 = 476 >= 456 chain length

__global__ __launch_bounds__(256) void inv_avgpool_kernel(
    const float* __restrict__ x, float* __restrict__ out) {
    __shared__ float xs[TLEN];
    __shared__ float outs[TLEN];
    __shared__ float partial[NCH][SEGS];

    const int row = blockIdx.x;
    const float* xr = x + (size_t)row * TLEN;
    float* outr = out + (size_t)row * TLEN;
    const int tid = threadIdx.x;

    // ---- stage row into LDS, coalesced float4 ----
    {
        const float4* src = (const float4*)xr;
        float4* dst = (float4*)xs;
        #pragma unroll
        for (int i = 0; i < TLEN / 4 / 256; ++i)
            dst[tid + i * 256] = src[tid + i * 256];
    }
    __syncthreads();

    const int r = tid / SEGS;   // chain id 0..8
    const int seg = tid % SEGS; // segment within chain
    const bool active = (tid < NCH * SEGS);

    // ---- pass 1: per-thread local sum of diffs, keep diffs in registers ----
    float d[SEGLEN];
    if (active) {
        float local = 0.f;
        const int m0 = seg * SEGLEN;
        #pragma unroll
        for (int i = 0; i < SEGLEN; ++i) {
            const int t = r + 9 * (m0 + i);
            float di = 0.f;
            if (t >= 1 && t < TLEN) di = xs[t] - xs[t - 1];
            d[i] = di;
            local += di;
        }
        partial[r][seg] = local;
    }
    __syncthreads();

    // ---- pass 2: serial exclusive prefix over 28 segment partials, then
    //      pass 3: inclusive scan of register diffs, write to LDS out buffer ----
    if (active) {
        float prefix = (r == 5) ? xs[0] : 0.f;  // the a[0]=K*x[0] seed on chain 5
        for (int s = 0; s < seg; ++s) prefix += partial[r][s];
        const int m0 = seg * SEGLEN;
        #pragma unroll
        for (int i = 0; i < SEGLEN; ++i) {
            const int t = r + 9 * (m0 + i);
            prefix += d[i];
            if (t < TLEN) outs[t] = 8.f * prefix;
        }
    }
    __syncthreads();

    // ---- coalesced float4 store ----
    {
        const float4* src = (const float4*)outs;
        float4* dst = (float4*)outr;
        #pragma unroll
        for (int i = 0; i < TLEN / 4 / 256; ++i)
            dst[tid + i * 256] = src[tid + i * 256];
    }
}

extern "C" void kernel_launch(void* const* d_in, const int* in_sizes, int n_in,
                              void* d_out, int out_size, void* d_ws, size_t ws_size,
                              hipStream_t stream) {
    const float* x = (const float*)d_in[0];
    float* out = (float*)d_out;
    const int rows = in_sizes[0] / TLEN;  // 64*256 = 16384
    inv_avgpool_kernel<<<rows, 256, 0, stream>>>(x, out);
}